// Round 1
// baseline (252.718 us; speedup 1.0000x reference)
//
#include <hip/hip_runtime.h>

// NavierStokesLossMAC: inputs (B=8, H=W=1024)
//   d_in[0] v_old  (B,2,H,W) f32
//   d_in[1] v_new  (B,2,H,W) f32
//   d_in[2] p_new  (B,1,H,W) f32
//   d_in[3] mask   (B,1,H,W) i32
// out: (B,) f32 = mean(res_x^2) + mean(res_y^2) over interior [1:-1,1:-1]

#define NS_H 1024
#define NS_W 1024

__global__ __launch_bounds__(256) void ns_loss_kernel(
    const float* __restrict__ v_old,
    const float* __restrict__ v_new,
    const float* __restrict__ p,
    const int*   __restrict__ mask,
    float* __restrict__ out)
{
    const int interior_rows = NS_H - 2;
    int blk = blockIdx.x;
    int b = blk / interior_rows;
    int y = 1 + (blk % interior_rows);

    const size_t hw = (size_t)NS_H * NS_W;
    const float* uo = v_old + (size_t)b * 2 * hw;        // u = channel 0
    const float* wo = uo + hw;                           // w = channel 1
    const float* un = v_new + (size_t)b * 2 * hw;
    const float* wn = un + hw;
    const float* pb = p    + (size_t)b * hw;
    const int*   mb = mask + (size_t)b * hw;

    const int row  = y * NS_W;
    const int rowm = row - NS_W;
    const int rowp = row + NS_W;

    float acc = 0.f;

    for (int x = 1 + (int)threadIdx.x; x <= NS_W - 2; x += (int)blockDim.x) {
        // center loads (reused for d/dt)
        float un_c = un[row + x],  uo_c = uo[row + x];
        float wn_c = wn[row + x],  wo_c = wo[row + x];

        float u_c  = 0.5f * (un_c + uo_c);
        float w_c  = 0.5f * (wn_c + wo_c);
        float u_xm = 0.5f * (un[row + x - 1] + uo[row + x - 1]);
        float u_xp = 0.5f * (un[row + x + 1] + uo[row + x + 1]);
        float u_ym = 0.5f * (un[rowm + x]    + uo[rowm + x]);
        float u_yp = 0.5f * (un[rowp + x]    + uo[rowp + x]);
        float w_xm = 0.5f * (wn[row + x - 1] + wo[row + x - 1]);
        float w_xp = 0.5f * (wn[row + x + 1] + wo[row + x + 1]);
        float w_ym = 0.5f * (wn[rowm + x]    + wo[rowm + x]);
        float w_yp = 0.5f * (wn[rowp + x]    + wo[rowp + x]);

        float p_c  = pb[row + x];
        float p_xm = pb[row + x - 1];
        float p_ym = pb[rowm + x];

        float m = (float)mb[row + x];

        // res_x: momentum in w (channel 1), derivatives: central-x, upwind-pair-y
        float res_x =
            (wn_c - wo_c) * 0.25f                                  // RHO*(w_new-w_old)/DT, RHO=1, DT=4
          + w_c * 0.5f * (w_xp - w_xm)                             // w * central-x(w)
          + 0.5f * ( 0.5f * (u_c + u_xm) * (w_c  - w_ym)           // velmap_left_x(u)*left_y(w)
                   + 0.5f * (u_c + u_xp) * (w_yp - w_c ) )         // velmap_right_x(u)*right_y(w)
          + (p_c - p_xm)                                           // left_x(p)
          - 0.1f * (w_xm + w_xp + w_ym + w_yp - 4.f * w_c);        // MU*lap(w)

        // res_y: momentum in u (channel 0)
        float res_y =
            (un_c - uo_c) * 0.25f
          + u_c * 0.5f * (u_yp - u_ym)                             // u * central-y(u)
          + 0.5f * ( 0.5f * (w_c + w_ym) * (u_c  - u_xm)           // velmap_left_y(w)*left_x(u)
                   + 0.5f * (w_c + w_yp) * (u_xp - u_c ) )         // velmap_right_y(w)*right_x(u)
          + (p_c - p_ym)                                           // left_y(p)
          - 0.1f * (u_xm + u_xp + u_ym + u_yp - 4.f * u_c);

        acc += m * (res_x * res_x + res_y * res_y);                // m in {0,1}: (m*r)^2 == m*r^2
    }

    // wave-64 reduction
    #pragma unroll
    for (int off = 32; off > 0; off >>= 1)
        acc += __shfl_down(acc, off);

    __shared__ float smem[4];
    int lane = threadIdx.x & 63;
    int wid  = threadIdx.x >> 6;
    if (lane == 0) smem[wid] = acc;
    __syncthreads();

    if (threadIdx.x == 0) {
        float t = smem[0] + smem[1] + smem[2] + smem[3];
        const float inv = 1.0f / ((float)(NS_H - 2) * (float)(NS_W - 2));
        atomicAdd(&out[b], t * inv);
    }
}

extern "C" void kernel_launch(void* const* d_in, const int* in_sizes, int n_in,
                              void* d_out, int out_size, void* d_ws, size_t ws_size,
                              hipStream_t stream) {
    const float* v_old = (const float*)d_in[0];
    const float* v_new = (const float*)d_in[1];
    const float* p_new = (const float*)d_in[2];
    const int*   msk   = (const int*)d_in[3];
    float* out = (float*)d_out;

    const int B = out_size;                 // 8
    // out is re-poisoned to 0xAA before every timed launch -> zero it on-stream
    hipMemsetAsync(d_out, 0, (size_t)out_size * sizeof(float), stream);

    dim3 grid(B * (NS_H - 2));
    dim3 block(256);
    ns_loss_kernel<<<grid, block, 0, stream>>>(v_old, v_new, p_new, msk, out);
}

// Round 2
// 252.109 us; speedup vs baseline: 1.0024x; 1.0024x over previous
//
#include <hip/hip_runtime.h>

// NavierStokesLossMAC: B=8, H=W=1024
//   d_in[0] v_old (B,2,H,W) f32 | d_in[1] v_new (B,2,H,W) f32
//   d_in[2] p_new (B,1,H,W) f32 | d_in[3] mask  (B,1,H,W) i32
// out: (B,) f32
//
// One block per (b, interior row y). float4-staged LDS rows; x-shifts from LDS.

#define NS_H 1024
#define NS_W 1024

__device__ __forceinline__ float4 ld4(const float* p) { return *(const float4*)p; }

__global__ __launch_bounds__(256) void ns_loss_kernel(
    const float* __restrict__ v_old,
    const float* __restrict__ v_new,
    const float* __restrict__ p,
    const int*   __restrict__ mask,
    float* __restrict__ out)
{
    const int interior_rows = NS_H - 2;
    const int blk = blockIdx.x;
    const int b = blk / interior_rows;
    const int y = 1 + (blk % interior_rows);

    const size_t hw = (size_t)NS_H * NS_W;
    const float* uo = v_old + (size_t)b * 2 * hw;
    const float* wo = uo + hw;
    const float* un = v_new + (size_t)b * 2 * hw;
    const float* wn = un + hw;
    const float* pb = p    + (size_t)b * hw;
    const int*   mb = mask + (size_t)b * hw;

    __shared__ float su[3][NS_W];   // avg u rows y-1,y,y+1
    __shared__ float sw[3][NS_W];   // avg w rows
    __shared__ float sdu[NS_W];     // (u_new - u_old) row y
    __shared__ float sdw[NS_W];     // (w_new - w_old) row y
    __shared__ float sp[2][NS_W];   // p rows y-1, y

    const int t  = threadIdx.x;
    const int x0 = t * 4;
    const int rm = (y - 1) * NS_W, rc = y * NS_W, rp = (y + 1) * NS_W;

    // ---- stage (15 independent dwordx4 loads, then LDS writes) ----
    float4 unm = ld4(un + rm + x0), uom = ld4(uo + rm + x0);
    float4 wnm = ld4(wn + rm + x0), wom = ld4(wo + rm + x0);
    float4 unc = ld4(un + rc + x0), uoc = ld4(uo + rc + x0);
    float4 wnc = ld4(wn + rc + x0), woc = ld4(wo + rc + x0);
    float4 unp = ld4(un + rp + x0), uop = ld4(uo + rp + x0);
    float4 wnp = ld4(wn + rp + x0), wop = ld4(wo + rp + x0);
    float4 ppm = ld4(pb + rm + x0);
    float4 ppc = ld4(pb + rc + x0);
    int4   m4  = *(const int4*)(mb + rc + x0);

    *(float4*)&su[0][x0] = make_float4(0.5f*(unm.x+uom.x), 0.5f*(unm.y+uom.y), 0.5f*(unm.z+uom.z), 0.5f*(unm.w+uom.w));
    *(float4*)&sw[0][x0] = make_float4(0.5f*(wnm.x+wom.x), 0.5f*(wnm.y+wom.y), 0.5f*(wnm.z+wom.z), 0.5f*(wnm.w+wom.w));
    *(float4*)&su[1][x0] = make_float4(0.5f*(unc.x+uoc.x), 0.5f*(unc.y+uoc.y), 0.5f*(unc.z+uoc.z), 0.5f*(unc.w+uoc.w));
    *(float4*)&sw[1][x0] = make_float4(0.5f*(wnc.x+woc.x), 0.5f*(wnc.y+woc.y), 0.5f*(wnc.z+woc.z), 0.5f*(wnc.w+woc.w));
    *(float4*)&su[2][x0] = make_float4(0.5f*(unp.x+uop.x), 0.5f*(unp.y+uop.y), 0.5f*(unp.z+uop.z), 0.5f*(unp.w+uop.w));
    *(float4*)&sw[2][x0] = make_float4(0.5f*(wnp.x+wop.x), 0.5f*(wnp.y+wop.y), 0.5f*(wnp.z+wop.z), 0.5f*(wnp.w+wop.w));
    *(float4*)&sdu[x0]   = make_float4(unc.x-uoc.x, unc.y-uoc.y, unc.z-uoc.z, unc.w-uoc.w);
    *(float4*)&sdw[x0]   = make_float4(wnc.x-woc.x, wnc.y-woc.y, wnc.z-woc.z, wnc.w-woc.w);
    *(float4*)&sp[0][x0] = ppm;
    *(float4*)&sp[1][x0] = ppc;

    __syncthreads();

    // ---- compute 4 columns per thread from LDS ----
    const int xl = (x0 > 0) ? x0 - 1 : 0;              // clamped; clamped value only feeds excluded x=0
    const int xr = (x0 + 4 < NS_W) ? x0 + 4 : NS_W - 1;

    float4 uc4  = ld4(&su[1][x0]);
    float  u_l  = su[1][xl], u_r = su[1][xr];
    float4 uym4 = ld4(&su[0][x0]);
    float4 uyp4 = ld4(&su[2][x0]);
    float4 wc4  = ld4(&sw[1][x0]);
    float  w_l  = sw[1][xl], w_r = sw[1][xr];
    float4 wym4 = ld4(&sw[0][x0]);
    float4 wyp4 = ld4(&sw[2][x0]);
    float4 du4  = ld4(&sdu[x0]);
    float4 dw4  = ld4(&sdw[x0]);
    float4 pc4  = ld4(&sp[1][x0]);
    float  p_l  = sp[1][xl];
    float4 pym4 = ld4(&sp[0][x0]);

    float uc[6]  = {u_l, uc4.x, uc4.y, uc4.z, uc4.w, u_r};
    float wc[6]  = {w_l, wc4.x, wc4.y, wc4.z, wc4.w, w_r};
    float pc[5]  = {p_l, pc4.x, pc4.y, pc4.z, pc4.w};
    float uym[4] = {uym4.x, uym4.y, uym4.z, uym4.w};
    float uyp[4] = {uyp4.x, uyp4.y, uyp4.z, uyp4.w};
    float wym[4] = {wym4.x, wym4.y, wym4.z, wym4.w};
    float wyp[4] = {wyp4.x, wyp4.y, wyp4.z, wyp4.w};
    float du[4]  = {du4.x, du4.y, du4.z, du4.w};
    float dw[4]  = {dw4.x, dw4.y, dw4.z, dw4.w};
    float pym[4] = {pym4.x, pym4.y, pym4.z, pym4.w};
    int   mm[4]  = {m4.x, m4.y, m4.z, m4.w};

    float acc = 0.f;
    #pragma unroll
    for (int j = 0; j < 4; ++j) {
        const int x = x0 + j;
        const float m = (x >= 1 && x <= NS_W - 2) ? (float)mm[j] : 0.f;

        const float u_c = uc[j+1], u_xm = uc[j], u_xp = uc[j+2];
        const float w_c = wc[j+1], w_xm = wc[j], w_xp = wc[j+2];

        float res_x =
            dw[j] * 0.25f
          + w_c * 0.5f * (w_xp - w_xm)
          + 0.5f * ( 0.5f * (u_c + u_xm) * (w_c    - wym[j])
                   + 0.5f * (u_c + u_xp) * (wyp[j] - w_c   ) )
          + (pc[j+1] - pc[j])
          - 0.1f * (w_xm + w_xp + wym[j] + wyp[j] - 4.f * w_c);

        float res_y =
            du[j] * 0.25f
          + u_c * 0.5f * (uyp[j] - uym[j])
          + 0.5f * ( 0.5f * (w_c + wym[j]) * (u_c  - u_xm)
                   + 0.5f * (w_c + wyp[j]) * (u_xp - u_c ) )
          + (pc[j+1] - pym[j])
          - 0.1f * (u_xm + u_xp + uym[j] + uyp[j] - 4.f * u_c);

        acc += m * (res_x * res_x + res_y * res_y);
    }

    // ---- reduce: wave shuffle -> LDS -> one atomic per block ----
    #pragma unroll
    for (int off = 32; off > 0; off >>= 1)
        acc += __shfl_down(acc, off);

    __shared__ float smem[4];
    const int lane = threadIdx.x & 63;
    const int wid  = threadIdx.x >> 6;
    if (lane == 0) smem[wid] = acc;
    __syncthreads();

    if (threadIdx.x == 0) {
        const float tsum = smem[0] + smem[1] + smem[2] + smem[3];
        const float inv = 1.0f / ((float)(NS_H - 2) * (float)(NS_W - 2));
        atomicAdd(&out[b], tsum * inv);
    }
}

extern "C" void kernel_launch(void* const* d_in, const int* in_sizes, int n_in,
                              void* d_out, int out_size, void* d_ws, size_t ws_size,
                              hipStream_t stream) {
    const float* v_old = (const float*)d_in[0];
    const float* v_new = (const float*)d_in[1];
    const float* p_new = (const float*)d_in[2];
    const int*   msk   = (const int*)d_in[3];
    float* out = (float*)d_out;

    hipMemsetAsync(d_out, 0, (size_t)out_size * sizeof(float), stream);

    dim3 grid(out_size * (NS_H - 2));   // 8 * 1022
    dim3 block(256);
    ns_loss_kernel<<<grid, block, 0, stream>>>(v_old, v_new, p_new, msk, out);
}

// Round 3
// 206.891 us; speedup vs baseline: 1.2215x; 1.2186x over previous
//
#include <hip/hip_runtime.h>

// NavierStokesLossMAC: B=8, H=W=1024
//   d_in[0] v_old (B,2,H,W) f32 | d_in[1] v_new (B,2,H,W) f32
//   d_in[2] p_new (B,1,H,W) f32 | d_in[3] mask  (B,1,H,W) i32
// out: (B,) f32
//
// Stage 1: one block per (b, interior row). float4-staged LDS rows; partial
//          sum stored to d_ws[blk] (distinct lines -> no atomic line-bounce;
//          R2's atomicAdd to one shared line cost ~125us of serialized
//          cross-XCD write-backs: WRITE_SIZE was exactly 8176*32B).
// Stage 2: 8 blocks reduce 1022 partials each -> out[b].

#define NS_H 1024
#define NS_W 1024
#define INT_ROWS (NS_H - 2)

__device__ __forceinline__ float4 ld4(const float* p) { return *(const float4*)p; }

__global__ __launch_bounds__(256) void ns_loss_partial(
    const float* __restrict__ v_old,
    const float* __restrict__ v_new,
    const float* __restrict__ p,
    const int*   __restrict__ mask,
    float* __restrict__ ws)
{
    const int blk = blockIdx.x;
    const int b = blk / INT_ROWS;
    const int y = 1 + (blk % INT_ROWS);

    const size_t hw = (size_t)NS_H * NS_W;
    const float* uo = v_old + (size_t)b * 2 * hw;
    const float* wo = uo + hw;
    const float* un = v_new + (size_t)b * 2 * hw;
    const float* wn = un + hw;
    const float* pb = p    + (size_t)b * hw;
    const int*   mb = mask + (size_t)b * hw;

    __shared__ float su[3][NS_W];
    __shared__ float sw[3][NS_W];
    __shared__ float sdu[NS_W];
    __shared__ float sdw[NS_W];
    __shared__ float sp[2][NS_W];

    const int t  = threadIdx.x;
    const int x0 = t * 4;
    const int rm = (y - 1) * NS_W, rc = y * NS_W, rp = (y + 1) * NS_W;

    float4 unm = ld4(un + rm + x0), uom = ld4(uo + rm + x0);
    float4 wnm = ld4(wn + rm + x0), wom = ld4(wo + rm + x0);
    float4 unc = ld4(un + rc + x0), uoc = ld4(uo + rc + x0);
    float4 wnc = ld4(wn + rc + x0), woc = ld4(wo + rc + x0);
    float4 unp = ld4(un + rp + x0), uop = ld4(uo + rp + x0);
    float4 wnp = ld4(wn + rp + x0), wop = ld4(wo + rp + x0);
    float4 ppm = ld4(pb + rm + x0);
    float4 ppc = ld4(pb + rc + x0);
    int4   m4  = *(const int4*)(mb + rc + x0);

    *(float4*)&su[0][x0] = make_float4(0.5f*(unm.x+uom.x), 0.5f*(unm.y+uom.y), 0.5f*(unm.z+uom.z), 0.5f*(unm.w+uom.w));
    *(float4*)&sw[0][x0] = make_float4(0.5f*(wnm.x+wom.x), 0.5f*(wnm.y+wom.y), 0.5f*(wnm.z+wom.z), 0.5f*(wnm.w+wom.w));
    *(float4*)&su[1][x0] = make_float4(0.5f*(unc.x+uoc.x), 0.5f*(unc.y+uoc.y), 0.5f*(unc.z+uoc.z), 0.5f*(unc.w+uoc.w));
    *(float4*)&sw[1][x0] = make_float4(0.5f*(wnc.x+woc.x), 0.5f*(wnc.y+woc.y), 0.5f*(wnc.z+woc.z), 0.5f*(wnc.w+woc.w));
    *(float4*)&su[2][x0] = make_float4(0.5f*(unp.x+uop.x), 0.5f*(unp.y+uop.y), 0.5f*(unp.z+uop.z), 0.5f*(unp.w+uop.w));
    *(float4*)&sw[2][x0] = make_float4(0.5f*(wnp.x+wop.x), 0.5f*(wnp.y+wop.y), 0.5f*(wnp.z+wop.z), 0.5f*(wnp.w+wop.w));
    *(float4*)&sdu[x0]   = make_float4(unc.x-uoc.x, unc.y-uoc.y, unc.z-uoc.z, unc.w-uoc.w);
    *(float4*)&sdw[x0]   = make_float4(wnc.x-woc.x, wnc.y-woc.y, wnc.z-woc.z, wnc.w-woc.w);
    *(float4*)&sp[0][x0] = ppm;
    *(float4*)&sp[1][x0] = ppc;

    __syncthreads();

    const int xl = (x0 > 0) ? x0 - 1 : 0;
    const int xr = (x0 + 4 < NS_W) ? x0 + 4 : NS_W - 1;

    float4 uc4  = ld4(&su[1][x0]);
    float  u_l  = su[1][xl], u_r = su[1][xr];
    float4 uym4 = ld4(&su[0][x0]);
    float4 uyp4 = ld4(&su[2][x0]);
    float4 wc4  = ld4(&sw[1][x0]);
    float  w_l  = sw[1][xl], w_r = sw[1][xr];
    float4 wym4 = ld4(&sw[0][x0]);
    float4 wyp4 = ld4(&sw[2][x0]);
    float4 du4  = ld4(&sdu[x0]);
    float4 dw4  = ld4(&sdw[x0]);
    float4 pc4  = ld4(&sp[1][x0]);
    float  p_l  = sp[1][xl];
    float4 pym4 = ld4(&sp[0][x0]);

    float uc[6]  = {u_l, uc4.x, uc4.y, uc4.z, uc4.w, u_r};
    float wc[6]  = {w_l, wc4.x, wc4.y, wc4.z, wc4.w, w_r};
    float pc[5]  = {p_l, pc4.x, pc4.y, pc4.z, pc4.w};
    float uym[4] = {uym4.x, uym4.y, uym4.z, uym4.w};
    float uyp[4] = {uyp4.x, uyp4.y, uyp4.z, uyp4.w};
    float wym[4] = {wym4.x, wym4.y, wym4.z, wym4.w};
    float wyp[4] = {wyp4.x, wyp4.y, wyp4.z, wyp4.w};
    float du[4]  = {du4.x, du4.y, du4.z, du4.w};
    float dw[4]  = {dw4.x, dw4.y, dw4.z, dw4.w};
    float pym[4] = {pym4.x, pym4.y, pym4.z, pym4.w};
    int   mm[4]  = {m4.x, m4.y, m4.z, m4.w};

    float acc = 0.f;
    #pragma unroll
    for (int j = 0; j < 4; ++j) {
        const int x = x0 + j;
        const float m = (x >= 1 && x <= NS_W - 2) ? (float)mm[j] : 0.f;

        const float u_c = uc[j+1], u_xm = uc[j], u_xp = uc[j+2];
        const float w_c = wc[j+1], w_xm = wc[j], w_xp = wc[j+2];

        float res_x =
            dw[j] * 0.25f
          + w_c * 0.5f * (w_xp - w_xm)
          + 0.5f * ( 0.5f * (u_c + u_xm) * (w_c    - wym[j])
                   + 0.5f * (u_c + u_xp) * (wyp[j] - w_c   ) )
          + (pc[j+1] - pc[j])
          - 0.1f * (w_xm + w_xp + wym[j] + wyp[j] - 4.f * w_c);

        float res_y =
            du[j] * 0.25f
          + u_c * 0.5f * (uyp[j] - uym[j])
          + 0.5f * ( 0.5f * (w_c + wym[j]) * (u_c  - u_xm)
                   + 0.5f * (w_c + wyp[j]) * (u_xp - u_c ) )
          + (pc[j+1] - pym[j])
          - 0.1f * (u_xm + u_xp + uym[j] + uyp[j] - 4.f * u_c);

        acc += m * (res_x * res_x + res_y * res_y);
    }

    #pragma unroll
    for (int off = 32; off > 0; off >>= 1)
        acc += __shfl_down(acc, off);

    __shared__ float smem[4];
    const int lane = threadIdx.x & 63;
    const int wid  = threadIdx.x >> 6;
    if (lane == 0) smem[wid] = acc;
    __syncthreads();

    if (threadIdx.x == 0)
        ws[blk] = smem[0] + smem[1] + smem[2] + smem[3];   // plain store, distinct lines
}

__global__ __launch_bounds__(256) void ns_loss_reduce(
    const float* __restrict__ ws, float* __restrict__ out)
{
    const int b = blockIdx.x;
    float acc = 0.f;
    for (int i = threadIdx.x; i < INT_ROWS; i += 256)
        acc += ws[b * INT_ROWS + i];

    #pragma unroll
    for (int off = 32; off > 0; off >>= 1)
        acc += __shfl_down(acc, off);

    __shared__ float smem[4];
    const int lane = threadIdx.x & 63;
    const int wid  = threadIdx.x >> 6;
    if (lane == 0) smem[wid] = acc;
    __syncthreads();

    if (threadIdx.x == 0) {
        const float inv = 1.0f / ((float)INT_ROWS * (float)(NS_W - 2));
        out[b] = (smem[0] + smem[1] + smem[2] + smem[3]) * inv;
    }
}

extern "C" void kernel_launch(void* const* d_in, const int* in_sizes, int n_in,
                              void* d_out, int out_size, void* d_ws, size_t ws_size,
                              hipStream_t stream) {
    const float* v_old = (const float*)d_in[0];
    const float* v_new = (const float*)d_in[1];
    const float* p_new = (const float*)d_in[2];
    const int*   msk   = (const int*)d_in[3];
    float* out = (float*)d_out;
    float* ws  = (float*)d_ws;

    const int B = out_size;   // 8

    ns_loss_partial<<<dim3(B * INT_ROWS), dim3(256), 0, stream>>>(v_old, v_new, p_new, msk, ws);
    ns_loss_reduce<<<dim3(B), dim3(256), 0, stream>>>(ws, out);
}

// Round 4
// 206.443 us; speedup vs baseline: 1.2242x; 1.0022x over previous
//
#include <hip/hip_runtime.h>

// NavierStokesLossMAC: B=8, H=W=1024
//   d_in[0] v_old (B,2,H,W) f32 | d_in[1] v_new (B,2,H,W) f32
//   d_in[2] p_new (B,1,H,W) f32 | d_in[3] mask  (B,1,H,W) i32
// out: (B,) f32
//
// R4: no LDS staging, no mid-kernel barrier. Each thread owns 4 columns:
// float4 center loads + scalar edge loads (x0-1, x0+4) that hit L1/L2 (same
// lines as neighbor threads' float4s). Edge-of-row reads spill into adjacent
// rows -> finite garbage feeding only masked-out columns (x=0/1023).
// LDS 41KB -> 16B frees occupancy (was 3 blocks/CU, barrier-serialized;
// R3: 3.2 TB/s @ 23.5% occupancy).
// Stage 2: 8 blocks reduce 1022 row-partials -> out[b] (no atomics; R2 showed
// same-line atomicAdd costs ~125us of serialized cross-XCD write-backs).

#define NS_H 1024
#define NS_W 1024
#define INT_ROWS (NS_H - 2)

__device__ __forceinline__ float4 ld4(const float* p) { return *(const float4*)p; }

__global__ __launch_bounds__(256) void ns_loss_partial(
    const float* __restrict__ v_old,
    const float* __restrict__ v_new,
    const float* __restrict__ p,
    const int*   __restrict__ mask,
    float* __restrict__ ws)
{
    const int blk = blockIdx.x;
    const int b = blk / INT_ROWS;
    const int y = 1 + (blk % INT_ROWS);

    const size_t hw = (size_t)NS_H * NS_W;
    const float* uo = v_old + (size_t)b * 2 * hw;
    const float* wo = uo + hw;
    const float* un = v_new + (size_t)b * 2 * hw;
    const float* wn = un + hw;
    const float* pb = p    + (size_t)b * hw;
    const int*   mb = mask + (size_t)b * hw;

    const int x0 = (int)threadIdx.x * 4;
    const int rm = (y - 1) * NS_W, rc = y * NS_W, rp = (y + 1) * NS_W;

    // center row y: float4 + 2 edge scalars per field (edges hit L1)
    float4 unc = ld4(un + rc + x0), uoc = ld4(uo + rc + x0);
    float  unl = un[rc + x0 - 1],   uol = uo[rc + x0 - 1];
    float  unr = un[rc + x0 + 4],   uor = uo[rc + x0 + 4];
    float4 wnc = ld4(wn + rc + x0), woc = ld4(wo + rc + x0);
    float  wnl = wn[rc + x0 - 1],   wol = wo[rc + x0 - 1];
    float  wnr = wn[rc + x0 + 4],   wor = wo[rc + x0 + 4];
    // rows y-1 / y+1: center 4 cols only
    float4 unm = ld4(un + rm + x0), uom = ld4(uo + rm + x0);
    float4 unp = ld4(un + rp + x0), uop = ld4(uo + rp + x0);
    float4 wnm = ld4(wn + rm + x0), wom = ld4(wo + rm + x0);
    float4 wnp = ld4(wn + rp + x0), wop = ld4(wo + rp + x0);
    // pressure: row y (+ left scalar), row y-1
    float4 pc4 = ld4(pb + rc + x0);
    float  p_l = pb[rc + x0 - 1];
    float4 pym4 = ld4(pb + rm + x0);
    int4   m4  = *(const int4*)(mb + rc + x0);

    const float uc[6] = {0.5f*(unl+uol), 0.5f*(unc.x+uoc.x), 0.5f*(unc.y+uoc.y),
                         0.5f*(unc.z+uoc.z), 0.5f*(unc.w+uoc.w), 0.5f*(unr+uor)};
    const float wc[6] = {0.5f*(wnl+wol), 0.5f*(wnc.x+woc.x), 0.5f*(wnc.y+woc.y),
                         0.5f*(wnc.z+woc.z), 0.5f*(wnc.w+woc.w), 0.5f*(wnr+wor)};
    const float uym[4] = {0.5f*(unm.x+uom.x), 0.5f*(unm.y+uom.y), 0.5f*(unm.z+uom.z), 0.5f*(unm.w+uom.w)};
    const float uyp[4] = {0.5f*(unp.x+uop.x), 0.5f*(unp.y+uop.y), 0.5f*(unp.z+uop.z), 0.5f*(unp.w+uop.w)};
    const float wym[4] = {0.5f*(wnm.x+wom.x), 0.5f*(wnm.y+wom.y), 0.5f*(wnm.z+wom.z), 0.5f*(wnm.w+wom.w)};
    const float wyp[4] = {0.5f*(wnp.x+wop.x), 0.5f*(wnp.y+wop.y), 0.5f*(wnp.z+wop.z), 0.5f*(wnp.w+wop.w)};
    const float du[4]  = {unc.x-uoc.x, unc.y-uoc.y, unc.z-uoc.z, unc.w-uoc.w};
    const float dw[4]  = {wnc.x-woc.x, wnc.y-woc.y, wnc.z-woc.z, wnc.w-woc.w};
    const float pc[5]  = {p_l, pc4.x, pc4.y, pc4.z, pc4.w};
    const float pym[4] = {pym4.x, pym4.y, pym4.z, pym4.w};
    const int   mm[4]  = {m4.x, m4.y, m4.z, m4.w};

    float acc = 0.f;
    #pragma unroll
    for (int j = 0; j < 4; ++j) {
        const int x = x0 + j;
        const float m = (x >= 1 && x <= NS_W - 2) ? (float)mm[j] : 0.f;

        const float u_c = uc[j+1], u_xm = uc[j], u_xp = uc[j+2];
        const float w_c = wc[j+1], w_xm = wc[j], w_xp = wc[j+2];

        float res_x =
            dw[j] * 0.25f
          + w_c * 0.5f * (w_xp - w_xm)
          + 0.5f * ( 0.5f * (u_c + u_xm) * (w_c    - wym[j])
                   + 0.5f * (u_c + u_xp) * (wyp[j] - w_c   ) )
          + (pc[j+1] - pc[j])
          - 0.1f * (w_xm + w_xp + wym[j] + wyp[j] - 4.f * w_c);

        float res_y =
            du[j] * 0.25f
          + u_c * 0.5f * (uyp[j] - uym[j])
          + 0.5f * ( 0.5f * (w_c + wym[j]) * (u_c  - u_xm)
                   + 0.5f * (w_c + wyp[j]) * (u_xp - u_c ) )
          + (pc[j+1] - pym[j])
          - 0.1f * (u_xm + u_xp + uym[j] + uyp[j] - 4.f * u_c);

        acc += m * (res_x * res_x + res_y * res_y);
    }

    // block reduction: wave shuffle -> 16B LDS -> one plain store per block
    #pragma unroll
    for (int off = 32; off > 0; off >>= 1)
        acc += __shfl_down(acc, off);

    __shared__ float smem[4];
    const int lane = threadIdx.x & 63;
    const int wid  = threadIdx.x >> 6;
    if (lane == 0) smem[wid] = acc;
    __syncthreads();

    if (threadIdx.x == 0)
        ws[blk] = smem[0] + smem[1] + smem[2] + smem[3];
}

__global__ __launch_bounds__(256) void ns_loss_reduce(
    const float* __restrict__ ws, float* __restrict__ out)
{
    const int b = blockIdx.x;
    float acc = 0.f;
    for (int i = threadIdx.x; i < INT_ROWS; i += 256)
        acc += ws[b * INT_ROWS + i];

    #pragma unroll
    for (int off = 32; off > 0; off >>= 1)
        acc += __shfl_down(acc, off);

    __shared__ float smem[4];
    const int lane = threadIdx.x & 63;
    const int wid  = threadIdx.x >> 6;
    if (lane == 0) smem[wid] = acc;
    __syncthreads();

    if (threadIdx.x == 0) {
        const float inv = 1.0f / ((float)INT_ROWS * (float)(NS_W - 2));
        out[b] = (smem[0] + smem[1] + smem[2] + smem[3]) * inv;
    }
}

extern "C" void kernel_launch(void* const* d_in, const int* in_sizes, int n_in,
                              void* d_out, int out_size, void* d_ws, size_t ws_size,
                              hipStream_t stream) {
    const float* v_old = (const float*)d_in[0];
    const float* v_new = (const float*)d_in[1];
    const float* p_new = (const float*)d_in[2];
    const int*   msk   = (const int*)d_in[3];
    float* out = (float*)d_out;
    float* ws  = (float*)d_ws;

    const int B = out_size;   // 8

    ns_loss_partial<<<dim3(B * INT_ROWS), dim3(256), 0, stream>>>(v_old, v_new, p_new, msk, ws);
    ns_loss_reduce<<<dim3(B), dim3(256), 0, stream>>>(ws, out);
}